// Round 5
// baseline (578.920 us; speedup 1.0000x reference)
//
#include <hip/hip_runtime.h>

// GCN 2-layer, N=100000, E=3200000, 13 -> 32 -> 16.
// v4: direct atomic CSR build (deg -> scan -> scatter) at full occupancy,
// replacing the 196-block two-level counting sort. k_agg = v2b (best measured).

constexpr int N_NODES = 100000;
constexpr int N_EDGES = 3200000;
constexpr int IN_CH  = 13;
constexpr int HID_CH = 32;
constexpr int LAT_CH = 16;
constexpr int NTOP = 196;        // ceil(100000/512)

__global__ __launch_bounds__(256) void k_zero(int* __restrict__ deg) {
    int i = blockIdx.x * 256 + threadIdx.x;
    if (i < N_NODES) deg[i] = 0;
}

// in-degree histogram: E global atomics over 100K counters (mean 32 hits each)
__global__ __launch_bounds__(256) void k_deg(const int* __restrict__ dst,
                                             int* __restrict__ deg) {
    int e = blockIdx.x * 256 + threadIdx.x;
    if (e < N_EDGES) atomicAdd(&deg[dst[e]], 1);
}

// per-512-node LDS scan: off[node] = local exclusive, bsum[b] = block total,
// dis[node] = rsqrt(deg+1)
__global__ __launch_bounds__(512) void k_scan1(const int* __restrict__ deg,
                                               int* __restrict__ off,
                                               float* __restrict__ dis,
                                               int* __restrict__ bsum) {
    __shared__ int ex[512];
    int b = blockIdx.x, tid = threadIdx.x;
    int node = b * 512 + tid;
    int d = (node < N_NODES) ? deg[node] : 0;
    ex[tid] = d;
    __syncthreads();
    for (int s = 1; s < 512; s <<= 1) {
        int a = ex[tid];
        int u = (tid >= s) ? ex[tid - s] : 0;
        __syncthreads();
        ex[tid] = a + u;
        __syncthreads();
    }
    if (node < N_NODES) {
        off[node] = ex[tid] - d;
        dis[node] = rsqrtf((float)(d + 1));   // +1 self-loop
    }
    if (tid == 511) bsum[b] = ex[511];
}

// exclusive scan of 196 block sums (one tiny block)
__global__ __launch_bounds__(256) void k_scanTop(const int* __restrict__ bsum,
                                                 int* __restrict__ bbase) {
    __shared__ int v[256];
    int tid = threadIdx.x;
    v[tid] = (tid < NTOP) ? bsum[tid] : 0;
    __syncthreads();
    for (int d = 1; d < 256; d <<= 1) {
        int a = v[tid];
        int u = (tid >= d) ? v[tid - d] : 0;
        __syncthreads();
        v[tid] = a + u;
        __syncthreads();
    }
    if (tid < NTOP) bbase[tid] = v[tid] - bsum[tid];
}

// add-back top-level bases; slot[] is the scatter cursor copy of off[]
__global__ __launch_bounds__(256) void k_add(int* __restrict__ off,
                                             int* __restrict__ slot,
                                             const int* __restrict__ bbase) {
    int i = blockIdx.x * 256 + threadIdx.x;
    if (i < N_NODES) {
        int v = off[i] + bbase[i >> 9];
        off[i] = v;
        slot[i] = v;
    } else if (i == N_NODES) {
        off[N_NODES] = N_EDGES;
    }
}

// CSR scatter: one atomic RMW per edge gives the slot directly
__global__ __launch_bounds__(256) void k_scatter(const int* __restrict__ src,
                                                 const int* __restrict__ dst,
                                                 int* __restrict__ slot,
                                                 int* __restrict__ srcs) {
    int e = blockIdx.x * 256 + threadIdx.x;
    if (e < N_EDGES) {
        int r = atomicAdd(&slot[dst[e]], 1);
        srcs[r] = src[e];
    }
}

// xn[i*16+c] = (c<13 ? x[i*13+c] : 0) * dis[i]
__global__ __launch_bounds__(256) void k_xn(const float* __restrict__ x,
                                            const float* __restrict__ dis,
                                            float* __restrict__ xn) {
    int idx = blockIdx.x * 256 + threadIdx.x;
    if (idx >= N_NODES * 16) return;
    int node = idx >> 4, c = idx & 15;
    xn[idx] = (c < IN_CH) ? x[node * IN_CH + c] * dis[node] : 0.f;
}

// 1 wave per node; 32 edge slots x 4 channel-quads (2x float4/lane); no atomics.
// Both gathers of a 32-slot window issue back-to-back (2 outstanding/lane);
// next window's srcs prefetched before consuming this window's gathers.
// outv[d*16+ch] = dis[d] * (sum_edges vin[s*16+ch] + vin[d*16+ch]) (+ bias)
__global__ __launch_bounds__(256) void k_agg(const int* __restrict__ off,
                                             const int* __restrict__ srcs,
                                             const float* __restrict__ dis,
                                             const float* __restrict__ vin,
                                             const float* __restrict__ bias,  // may be null
                                             float* __restrict__ outv) {
    int wave = (blockIdx.x * 256 + threadIdx.x) >> 6;
    int lane = threadIdx.x & 63;
    int q    = lane & 3;       // channel quad: floats q*4 .. q*4+3
    int esub = lane >> 2;      // edge slot 0..15 (and +16 for second buffer)
    if (wave >= N_NODES) return;
    int beg = off[wave], end = off[wave + 1];

    float ax = 0.f, ay = 0.f, az = 0.f, aw = 0.f;
    int k1 = beg + esub;
    int k2 = k1 + 16;
    int s1 = (k1 < end) ? srcs[k1] : -1;
    int s2 = (k2 < end) ? srcs[k2] : -1;
    for (int kb = beg; kb < end; kb += 32) {
        int kn = kb + 32 + esub;
        int sn1 = (kn < end)      ? srcs[kn]      : -1;
        int sn2 = (kn + 16 < end) ? srcs[kn + 16] : -1;
        float4 v1, v2;
        v1.x = v1.y = v1.z = v1.w = 0.f;
        v2.x = v2.y = v2.z = v2.w = 0.f;
        if (s1 >= 0) v1 = *((const float4*)(vin + (size_t)s1 * 16) + q);
        if (s2 >= 0) v2 = *((const float4*)(vin + (size_t)s2 * 16) + q);
        ax += v1.x + v2.x;
        ay += v1.y + v2.y;
        az += v1.z + v2.z;
        aw += v1.w + v2.w;
        s1 = sn1; s2 = sn2;
    }
#pragma unroll
    for (int m = 4; m <= 32; m <<= 1) {        // reduce over esub (lane bits 2..5)
        ax += __shfl_xor(ax, m);
        ay += __shfl_xor(ay, m);
        az += __shfl_xor(az, m);
        aw += __shfl_xor(aw, m);
    }
    if (esub == 0) {
        const float4 self = *((const float4*)(vin + (size_t)wave * 16) + q);
        float d = dis[wave];
        float4 r;
        r.x = d * (ax + self.x);
        r.y = d * (ay + self.y);
        r.z = d * (az + self.z);
        r.w = d * (aw + self.w);
        if (bias) {
            const float4 bq = ((const float4*)bias)[q];
            r.x += bq.x; r.y += bq.y; r.z += bq.z; r.w += bq.w;
        }
        *((float4*)(outv + (size_t)wave * 16) + q) = r;
    }
}

// fused: hwn = (relu(s1 @ W1 + b1) @ W2) * dis   (per node, through LDS)
__global__ __launch_bounds__(256) void k_gemm12(const float* __restrict__ s1,
                                                const float* __restrict__ W1,
                                                const float* __restrict__ b1,
                                                const float* __restrict__ W2,
                                                const float* __restrict__ dis,
                                                float* __restrict__ hwn) {
    __shared__ float sW1[IN_CH * HID_CH];
    __shared__ float sW2[HID_CH * LAT_CH];
    __shared__ float sr[8][HID_CH + 1];
    int tid = threadIdx.x;
    for (int i = tid; i < IN_CH * HID_CH; i += 256) sW1[i] = W1[i];
    for (int i = tid; i < HID_CH * LAT_CH; i += 256) sW2[i] = W2[i];
    __syncthreads();
    int nl = tid >> 5, c1 = tid & 31;
    int node = blockIdx.x * 8 + nl;
    float r = 0.f;
    if (node < N_NODES) {
        float acc = b1[c1];
#pragma unroll
        for (int k = 0; k < IN_CH; ++k)
            acc += s1[node * 16 + k] * sW1[k * HID_CH + c1];
        r = acc > 0.f ? acc : 0.f;   // ReLU
    }
    sr[nl][c1] = r;
    __syncthreads();
    if (tid < 128) {
        int nl2 = tid >> 4, c2 = tid & 15;
        int node2 = blockIdx.x * 8 + nl2;
        if (node2 < N_NODES) {
            float acc = 0.f;
#pragma unroll
            for (int k = 0; k < HID_CH; ++k)
                acc += sr[nl2][k] * sW2[k * LAT_CH + c2];
            hwn[node2 * 16 + c2] = acc * dis[node2];
        }
    }
}

extern "C" void kernel_launch(void* const* d_in, const int* in_sizes, int n_in,
                              void* d_out, int out_size, void* d_ws, size_t ws_size,
                              hipStream_t stream) {
    const float* x  = (const float*)d_in[0];
    const int*   ei = (const int*)d_in[1];
    const float* W1 = (const float*)d_in[2];
    const float* b1 = (const float*)d_in[3];
    const float* W2 = (const float*)d_in[4];
    const float* b2 = (const float*)d_in[5];
    float* out = (float*)d_out;

    const int* src = ei;
    const int* dst = ei + N_EDGES;

    // ws layout (bytes):
    //   deg  @ 0        (400000)
    //   off  @ 400000   (400064, N+1 ints)
    //   slot @ 800064   (400000)
    //   dis  @ 1200064  (400000)
    //   bsum @ 1600064  (1024)
    //   bbase@ 1601088  (1024)
    //   srcs @ 1602112  (12.8MB)
    //   xn   @ 14402112 (6.4MB)   s1 @ 20802112 (6.4MB)   hwn aliases xn
    char* ws = (char*)d_ws;
    int*   deg   = (int*)(ws);
    int*   off   = (int*)(ws + 400000);
    int*   slot  = (int*)(ws + 800064);
    float* dis   = (float*)(ws + 1200064);
    int*   bsum  = (int*)(ws + 1600064);
    int*   bbase = (int*)(ws + 1601088);
    int*   srcs  = (int*)(ws + 1602112);
    float* xn    = (float*)(ws + 14402112);
    float* s1    = (float*)(ws + 20802112);
    float* hwn   = xn;  // xn dead after first k_agg

    const int NB_E  = (N_EDGES + 255) / 256;            // 12500
    const int NB_N  = (N_NODES + 255) / 256;            // 391
    const int NB_N1 = (N_NODES + 1 + 255) / 256;        // 391
    const int NB_N16= (N_NODES * 16 + 255) / 256;
    const int NB_W  = (N_NODES + 3) / 4;                // 1 wave/node, 4 waves/block
    const int NB_G  = (N_NODES + 7) / 8;

    k_zero   <<<NB_N,  256, 0, stream>>>(deg);
    k_deg    <<<NB_E,  256, 0, stream>>>(dst, deg);
    k_scan1  <<<NTOP,  512, 0, stream>>>(deg, off, dis, bsum);
    k_scanTop<<<1,     256, 0, stream>>>(bsum, bbase);
    k_add    <<<NB_N1, 256, 0, stream>>>(off, slot, bbase);
    k_scatter<<<NB_E,  256, 0, stream>>>(src, dst, slot, srcs);
    k_xn     <<<NB_N16,256, 0, stream>>>(x, dis, xn);
    k_agg    <<<NB_W,  256, 0, stream>>>(off, srcs, dis, xn, nullptr, s1);
    k_gemm12 <<<NB_G,  256, 0, stream>>>(s1, W1, b1, W2, dis, hwn);
    k_agg    <<<NB_W,  256, 0, stream>>>(off, srcs, dis, hwn, b2, out);
}